// Round 16
// baseline (161.569 us; speedup 1.0000x reference)
//
#include <hip/hip_runtime.h>
#include <hip/hip_bf16.h>
#include <math.h>

// Problem constants
#define BB 2
#define LL 4096
#define DD 2048
#define KK 32
#define MEM 256          // K*H
#define CTOT 288         // MEM+K
#define NQ 512           // KQ*H*M*2
#define ZSTR 800         // CTOT + NQ (combined z|q GEMM output stride)
#define NPAD 896         // padded N for combined GEMM (7*128)
#define FLAT 2048        // K*H*M
#define CMERG 4128       // K + 2*FLAT
#define CH 16            // scan chunk length
#define NCH 256          // L / CH
#define YDIM 768         // K*24
#define BL (BB*LL)       // 8192

typedef __attribute__((ext_vector_type(4))) float f32x4;
typedef __attribute__((ext_vector_type(8))) short bf16x8;
typedef __attribute__((ext_vector_type(8))) unsigned short u16x8;

__device__ inline unsigned short f2b(float v) {
    __hip_bfloat16 h = __float2bfloat16(v);
    return *reinterpret_cast<unsigned short*>(&h);
}
__device__ inline float b2f(unsigned short u) {
    __hip_bfloat16 h;
    *reinterpret_cast<unsigned short*>(&h) = u;
    return __bfloat162float(h);
}

__device__ inline void gload16(const void* g, void* l) {
    __builtin_amdgcn_global_load_lds(
        (const __attribute__((address_space(1))) unsigned int*)g,
        (__attribute__((address_space(3))) unsigned int*)l, 16, 0, 0);
}

// vmcnt ladder for gemm256's 4-buffer pipeline (4 loads per stage)
__device__ inline void wait_stage(int it, int nIter) {
    if (it + 3 <= nIter) asm volatile("s_waitcnt vmcnt(8)" ::: "memory");
    else if (it + 2 == nIter) asm volatile("s_waitcnt vmcnt(4)" ::: "memory");
    else asm volatile("s_waitcnt vmcnt(0)" ::: "memory");
}

// broadcast lane (group_base | HH) within aligned 8-lane groups (BitMode swizzle)
template<int HH>
__device__ inline float bcast8(float v) {
    return __int_as_float(__builtin_amdgcn_ds_swizzle(__float_as_int(v), (HH << 5) | 0x18));
}

__device__ inline float fast_sigmoid_mul(float val, float g) {
    return val * __builtin_amdgcn_rcpf(1.f + __expf(-g));
}

// ---------------- weight preps ----------------
__global__ __launch_bounds__(256) void prep_wb(const float* __restrict__ W_mem,
                                               const float* __restrict__ W_q,
                                               unsigned short* __restrict__ Wb) {
    int n = blockIdx.x;   // 0..895
    for (int k = threadIdx.x; k < DD; k += 256) {
        float v = 0.f;
        if (n < CTOT) v = W_mem[(size_t)k * CTOT + n];
        else if (n < ZSTR) v = W_q[(size_t)k * NQ + (n - CTOT)];
        Wb[(size_t)n * DD + k] = f2b(v);
    }
}

// W_out^T as [N=2048][K=768] bf16
__global__ __launch_bounds__(256) void prep_wo(const float* __restrict__ W_out,
                                               unsigned short* __restrict__ Wo) {
    int n = blockIdx.x;   // 0..2047
    for (int k = threadIdx.x; k < YDIM; k += 256) {
        Wo[(size_t)n * YDIM + k] = f2b(W_out[(size_t)k * DD + n]);
    }
}

// ---------------- 128x128 MFMA GEMM (zq): A f32 in HBM, reg-staged -> bf16 LDS ----------------
// A: global_load_dwordx4 x4 -> f2b in reg -> 2x ds_write_b128 into the PROVEN 0-conflict
// bf16 tile (4 slots/row, swizzle s^((row>>1)&3)). Regs for tile t+2 loaded at iter t
// (1 full iter before their ds_write). B: global_load_lds, counted vmcnt before raw barrier.
__global__ __launch_bounds__(256) void gemm_zq(const float* __restrict__ Af,
                                               const unsigned short* __restrict__ Bh_g,
                                               unsigned short* __restrict__ Cout,
                                               int Kd, int Nvalid, int Cstride) {
    __shared__ __attribute__((aligned(16))) unsigned short As[2][4096];  // 128x32 bf16, 8 KB/buf
    __shared__ __attribute__((aligned(16))) unsigned short Bh[2][4096];
    int tid = threadIdx.x;
    int lane = tid & 63;
    int wave = tid >> 6;
    int wr = wave >> 1, wc = wave & 1;

    int nwg = gridDim.x * gridDim.y;
    int bid = blockIdx.y * gridDim.x + blockIdx.x;
    int cpx = nwg >> 3;
    int swz = (bid & 7) * cpx + (bid >> 3);
    int bx = swz % gridDim.x, by = swz / gridDim.x;
    int m0 = by * 128;
    int n0 = bx * 128;

    f32x4 acc[4][4];
#pragma unroll
    for (int i = 0; i < 4; ++i)
#pragma unroll
        for (int j = 0; j < 4; ++j) acc[i][j] = (f32x4){0.f, 0.f, 0.f, 0.f};

    // A: thread handles bf16-slots f0=tid, f1=tid+256 (512 slots of 16B = 128x32 bf16)
    // slot f: row=f>>2, s=f&3, global slot sg = s^((row>>1)&3); data = 8 f32 at col sg*8
    int fa0 = tid, fa1 = tid + 256;
    int rowA0 = fa0 >> 2, sA0 = (fa0 & 3) ^ ((rowA0 >> 1) & 3);
    int rowA1 = fa1 >> 2, sA1 = (fa1 & 3) ^ ((rowA1 >> 1) & 3);
    const float* gA0 = Af + (size_t)(m0 + rowA0) * Kd + sA0 * 8;
    const float* gA1 = Af + (size_t)(m0 + rowA1) * Kd + sA1 * 8;

    // B staging (global_load_lds): 512 slots, 2 per thread
    const unsigned short* pB[2];
    int offB[2];
#pragma unroll
    for (int j = 0; j < 2; ++j) {
        int f = j * 256 + tid;
        int row = f >> 2, s = f & 3;
        int sg = s ^ ((row >> 1) & 3);
        pB[j] = Bh_g + (size_t)(n0 + row) * Kd + sg * 8;
        offB[j] = f * 8;
    }

    int g = lane >> 4, rr = lane & 15;
    int nIter = Kd >> 5;    // 64

#define LOADA(k0) do {                                                  \
        ra0 = *(const f32x4*)(gA0 + (k0));                              \
        ra1 = *(const f32x4*)(gA0 + (k0) + 4);                          \
        ra2 = *(const f32x4*)(gA1 + (k0));                              \
        ra3 = *(const f32x4*)(gA1 + (k0) + 4);                          \
    } while (0)
#define WRITEA(buf) do {                                                \
        u16x8 w0, w1;                                                   \
        w0[0] = f2b(ra0[0]); w0[1] = f2b(ra0[1]); w0[2] = f2b(ra0[2]); w0[3] = f2b(ra0[3]); \
        w0[4] = f2b(ra1[0]); w0[5] = f2b(ra1[1]); w0[6] = f2b(ra1[2]); w0[7] = f2b(ra1[3]); \
        w1[0] = f2b(ra2[0]); w1[1] = f2b(ra2[1]); w1[2] = f2b(ra2[2]); w1[3] = f2b(ra2[3]); \
        w1[4] = f2b(ra3[0]); w1[5] = f2b(ra3[1]); w1[6] = f2b(ra3[2]); w1[7] = f2b(ra3[3]); \
        *(u16x8*)&As[buf][fa0 * 8] = w0;                                \
        *(u16x8*)&As[buf][fa1 * 8] = w1;                                \
    } while (0)

    f32x4 ra0, ra1, ra2, ra3;
    // prologue
    LOADA(0);                              // regs <- tile0  [vm: 4]
    gload16(pB[0], &Bh[0][offB[0]]);       // B0             [vm: 4+2]
    gload16(pB[1], &Bh[0][offB[1]]);
    WRITEA(0);                             // compiler waits regs (vmcnt<=2), writes Abuf0
    LOADA(32);                             // regs <- tile1  [vm: B0(2) + regs(4)]
    asm volatile("s_waitcnt vmcnt(4) lgkmcnt(0)" ::: "memory");  // B0 landed, Abuf0 written
    __builtin_amdgcn_s_barrier();

    for (int it = 0; it < nIter; ++it) {
        int buf = it & 1, nxt = buf ^ 1;
        bool h1 = (it + 1 < nIter);
        bool h2 = (it + 2 < nIter);
        if (h1) {
            WRITEA(nxt);                                   // tile it+1 (regs from last iter)
            gload16(pB[0] + (it + 1) * 32, &Bh[nxt][offB[0]]);
            gload16(pB[1] + (it + 1) * 32, &Bh[nxt][offB[1]]);
        }
        if (h2) LOADA((it + 2) * 32);                      // regs <- tile it+2

        bf16x8 av[4], bhv[4];
#pragma unroll
        for (int i = 0; i < 4; ++i) {
            int ra = wr * 64 + i * 16 + rr;
            av[i] = *(const bf16x8*)&As[buf][ra * 32 + ((g ^ ((ra >> 1) & 3)) * 8)];
            int rb = wc * 64 + i * 16 + rr;
            bhv[i] = *(const bf16x8*)&Bh[buf][rb * 32 + ((g ^ ((rb >> 1) & 3)) * 8)];
        }
#pragma unroll
        for (int i = 0; i < 4; ++i)
#pragma unroll
            for (int j = 0; j < 4; ++j)
                acc[i][j] = __builtin_amdgcn_mfma_f32_16x16x32_bf16(av[i], bhv[j], acc[i][j], 0, 0, 0);

        if (h1) {
            if (h2) asm volatile("s_waitcnt vmcnt(4) lgkmcnt(0)" ::: "memory");  // B(it+1) landed; A-regs fly
            else    asm volatile("s_waitcnt vmcnt(0) lgkmcnt(0)" ::: "memory");
            __builtin_amdgcn_s_barrier();
        }
    }
#undef LOADA
#undef WRITEA

    int cg = lane >> 4, cr = lane & 15;
#pragma unroll
    for (int i = 0; i < 4; ++i)
#pragma unroll
        for (int j = 0; j < 4; ++j) {
            int colb = n0 + wc * 64 + j * 16 + cr;
            if (colb < Nvalid) {
#pragma unroll
                for (int r = 0; r < 4; ++r) {
                    int rowb = m0 + wr * 64 + i * 16 + cg * 4 + r;
                    Cout[(size_t)rowb * Cstride + colb] = f2b(acc[i][j][r]);
                }
            }
        }
}

// ---------------- 256x256 8-wave GEMM (final), BK=32, 4-buffer distance-2 pipeline ----------------
__global__ __launch_bounds__(512, 2) void gemm256(const unsigned short* __restrict__ A,
                                                  const unsigned short* __restrict__ Bm,
                                                  float* __restrict__ C,
                                                  int Kd, int Cstride) {
    __shared__ __attribute__((aligned(16))) unsigned short As[4][8192];
    __shared__ __attribute__((aligned(16))) unsigned short Bs[4][8192];
    int tid = threadIdx.x;
    int lane = tid & 63, wave = tid >> 6;
    int wm = wave >> 2, wn = wave & 3;

    int nwg = gridDim.x * gridDim.y;            // 256
    int bid = blockIdx.y * gridDim.x + blockIdx.x;
    int cpx = nwg >> 3;
    int swz = (bid & 7) * cpx + (bid >> 3);
    int bx = swz % gridDim.x, by = swz / gridDim.x;
    int m0 = by * 256, n0 = bx * 256;

    f32x4 acc[8][4];
#pragma unroll
    for (int i = 0; i < 8; ++i)
#pragma unroll
        for (int j = 0; j < 4; ++j) acc[i][j] = (f32x4){0.f, 0.f, 0.f, 0.f};

    const unsigned short* pA[2];
    const unsigned short* pB[2];
    int ldsoff[2];
#pragma unroll
    for (int j = 0; j < 2; ++j) {
        int f = j * 512 + tid;
        int row = f >> 2, s = f & 3;
        int sg = s ^ ((row >> 1) & 3);
        pA[j] = A + (size_t)(m0 + row) * Kd + sg * 8;
        pB[j] = Bm + (size_t)(n0 + row) * Kd + sg * 8;
        ldsoff[j] = (j * 512 + wave * 64) * 8;
    }

    int rr = lane & 15, kg = lane >> 4;

#define STAGE(buf, koff) do {                                          \
        gload16(pA[0] + (koff), &As[buf][ldsoff[0]]);                  \
        gload16(pA[1] + (koff), &As[buf][ldsoff[1]]);                  \
        gload16(pB[0] + (koff), &Bs[buf][ldsoff[0]]);                  \
        gload16(pB[1] + (koff), &Bs[buf][ldsoff[1]]);                  \
    } while (0)

    int nT = Kd >> 5;       // 24
    STAGE(0, 0);
    STAGE(1, 32);

#define LDA(fr) ({ int ra_ = wm * 128 + (fr) * 16 + rr;                          \
        *(const bf16x8*)&As[cur][ra_ * 32 + ((kg ^ ((ra_ >> 1) & 3)) * 8)]; })
#define LDB(fc) ({ int rb_ = wn * 64 + (fc) * 16 + rr;                           \
        *(const bf16x8*)&Bs[cur][rb_ * 32 + ((kg ^ ((rb_ >> 1) & 3)) * 8)]; })

    for (int it = 0; it < nT; ++it) {
        int cur = it & 3;
        if (it + 2 < nT) STAGE((it + 2) & 3, (it + 2) * 32);
        wait_stage(it, nT);
        __builtin_amdgcn_s_barrier();

        bf16x8 bv[4];
#pragma unroll
        for (int j = 0; j < 4; ++j) bv[j] = LDB(j);
#pragma unroll
        for (int i = 0; i < 8; ++i) {
            bf16x8 a0 = LDA(i);
#pragma unroll
            for (int j = 0; j < 4; ++j)
                acc[i][j] = __builtin_amdgcn_mfma_f32_16x16x32_bf16(a0, bv[j], acc[i][j], 0, 0, 0);
        }
    }
#undef LDA
#undef LDB
#undef STAGE

    int cg = lane >> 4;
#pragma unroll
    for (int i = 0; i < 8; ++i)
#pragma unroll
        for (int j = 0; j < 4; ++j) {
            int colb = n0 + wn * 64 + j * 16 + rr;
#pragma unroll
            for (int r = 0; r < 4; ++r) {
                int rowb = m0 + wm * 128 + i * 16 + cg * 4 + r;
                C[(size_t)rowb * Cstride + colb] = acc[i][j][r];
            }
        }
}

// ---------------- fused A: conv+trig chunk partial sums ----------------
__global__ __launch_bounds__(256) void fused_partial(const unsigned short* __restrict__ zq,
                                                     const float* __restrict__ conv_k,
                                                     const float* __restrict__ theta,
                                                     const float* __restrict__ decay,
                                                     const float* __restrict__ anchor,
                                                     const float* __restrict__ sscale,
                                                     float* __restrict__ partials) {
    int chunk = blockIdx.x, b = blockIdx.y, t = threadIdx.x;
    int l0 = chunk * CH;
    __shared__ unsigned short zin[CH + 3][CTOT];

    for (int idx = t; idx < (CH + 3) * 36; idx += 256) {
        int r = idx / 36, c8 = (idx % 36) * 8;
        int l = l0 - 3 + r;
        u16x8 v = (u16x8)(0);
        if (l >= 0) v = *(const u16x8*)&zq[(size_t)(b * LL + l) * ZSTR + c8];
        *(u16x8*)&zin[r][c8] = v;
    }
    __syncthreads();

    int k = t >> 3;
    float cz0 = conv_k[t], cz1 = conv_k[CTOT + t], cz2 = conv_k[2 * CTOT + t], cz3 = conv_k[3 * CTOT + t];
    int sc = MEM + k;
    float cs0 = conv_k[sc], cs1 = conv_k[CTOT + sc], cs2 = conv_k[2 * CTOT + sc], cs3 = conv_k[3 * CTOT + sc];
    float xx = (k < KK - 4) ? decay[k] : anchor[k - (KK - 4)];
    float sp = (xx > 20.f) ? xx : log1pf(__expf(xx));
    float ss = sscale[k];
    float th[8];
#pragma unroll
    for (int m = 0; m < 8; ++m) th[m] = theta[t * 8 + m];
    float rs[8], is[8];
#pragma unroll
    for (int m = 0; m < 8; ++m) { rs[m] = 0.f; is[m] = 0.f; }
    float dsum = 0.f;

#pragma unroll 1
    for (int i = 0; i < CH; ++i) {
        float kv = b2f(zin[i][t]) * cz0 + b2f(zin[i + 1][t]) * cz1 +
                   b2f(zin[i + 2][t]) * cz2 + b2f(zin[i + 3][t]) * cz3;
        float s = b2f(zin[i][sc]) * cs0 + b2f(zin[i + 1][sc]) * cs1 +
                  b2f(zin[i + 2][sc]) * cs2 + b2f(zin[i + 3][sc]) * cs3;
        int l = l0 + i;
        float lw = (k < KK - 4) ? -sp * (float)(LL - 1 - l) : -sp * (float)l;
        float lp = fminf(fmaxf(ss * s, -20.f), 20.f);
        float p = __expf(lp + lw);
        dsum += p;
#pragma unroll
        for (int m = 0; m < 8; ++m) {
            float sn, cn;
            __sincosf(kv * th[m], &sn, &cn);
            rs[m] += p * cn;
            is[m] += p * sn;
        }
    }
    size_t base = ((size_t)b * NCH + chunk) * CMERG;
    *(f32x4*)&partials[base + KK + t * 8]            = (f32x4){rs[0], rs[1], rs[2], rs[3]};
    *(f32x4*)&partials[base + KK + t * 8 + 4]        = (f32x4){rs[4], rs[5], rs[6], rs[7]};
    *(f32x4*)&partials[base + KK + FLAT + t * 8]     = (f32x4){is[0], is[1], is[2], is[3]};
    *(f32x4*)&partials[base + KK + FLAT + t * 8 + 4] = (f32x4){is[4], is[5], is[6], is[7]};
    if ((t & 7) == 0) partials[base + k] = dsum;
}

// ---------------- fused B: exclusive scan of chunk partials (in place) ----------------
__global__ __launch_bounds__(256) void scan_partials(float* __restrict__ partials) {
    int t = threadIdx.x;
    int cl = t & 15, j = t >> 4;
    int c = blockIdx.x * 16 + cl;
    int b = blockIdx.y;
    float v[16];
    float s = 0.f;
#pragma unroll
    for (int i = 0; i < 16; ++i) {
        v[i] = partials[((size_t)b * NCH + j * 16 + i) * CMERG + c];
        s += v[i];
    }
    __shared__ float sums[16][17];
    sums[j][cl] = s;
    __syncthreads();
    if (j == 0) {
        float run = 0.f;
#pragma unroll
        for (int jj = 0; jj < 16; ++jj) {
            float x = sums[jj][cl];
            sums[jj][cl] = run;
            run += x;
        }
    }
    __syncthreads();
    float run = sums[j][cl];
#pragma unroll
    for (int i = 0; i < 16; ++i) {
        float x = v[i];
        partials[((size_t)b * NCH + j * 16 + i) * CMERG + c] = run;
        run += x;
    }
}

// ---------------- fused C: recompute + in-register scan + stage_d ----------------
__global__ __launch_bounds__(256) void fused_stage(const unsigned short* __restrict__ zq,
                                                   const float* __restrict__ conv_k,
                                                   const float* __restrict__ theta,
                                                   const float* __restrict__ decay,
                                                   const float* __restrict__ anchor,
                                                   const float* __restrict__ sscale,
                                                   const float* __restrict__ partials,
                                                   const float* __restrict__ W_re,
                                                   const float* __restrict__ W_im,
                                                   const float* __restrict__ nscale,
                                                   unsigned short* __restrict__ y_act) {
    int chunk = blockIdx.x, b = blockIdx.y, t = threadIdx.x;
    int l0 = chunk * CH;
    __shared__ unsigned short zin[CH + 3][CTOT];
    __shared__ unsigned short qall[CH][NQ];

    for (int idx = t; idx < (CH + 3) * 36; idx += 256) {
        int r = idx / 36, c8 = (idx % 36) * 8;
        int l = l0 - 3 + r;
        u16x8 v = (u16x8)(0);
        if (l >= 0) v = *(const u16x8*)&zq[(size_t)(b * LL + l) * ZSTR + c8];
        *(u16x8*)&zin[r][c8] = v;
    }
    for (int idx = t; idx < CH * (NQ / 8); idx += 256) {
        int i = idx >> 6, c8 = (idx & 63) * 8;
        *(u16x8*)&qall[i][c8] = *(const u16x8*)&zq[(size_t)(b * LL + l0 + i) * ZSTR + CTOT + c8];
    }
    __syncthreads();

    int k = t >> 3, h = t & 7, w = t >> 6;
    float cz0 = conv_k[t], cz1 = conv_k[CTOT + t], cz2 = conv_k[2 * CTOT + t], cz3 = conv_k[3 * CTOT + t];
    int sc = MEM + k;
    float cs0 = conv_k[sc], cs1 = conv_k[CTOT + sc], cs2 = conv_k[2 * CTOT + sc], cs3 = conv_k[3 * CTOT + sc];
    float xx = (k < KK - 4) ? decay[k] : anchor[k - (KK - 4)];
    float sp = (xx > 20.f) ? xx : log1pf(__expf(xx));
    float ss = sscale[k];
    float th[8];
#pragma unroll
    for (int m = 0; m < 8; ++m) th[m] = theta[t * 8 + m];
    float ns = nscale[t];
    int qb = w * 128 + h * 16;

    float wre[8][6], wim[8][6];
#pragma unroll
    for (int hh = 0; hh < 8; ++hh)
#pragma unroll
        for (int jj = 0; jj < 6; ++jj) {
            wre[hh][jj] = W_re[(k * 8 + hh) * 48 + h + 8 * jj];
            wim[hh][jj] = W_im[(k * 8 + hh) * 48 + h + 8 * jj];
        }

    size_t pbase = ((size_t)b * NCH + chunk) * CMERG;
    f32x4 r0 = *(const f32x4*)&partials[pbase + KK + t * 8];
    f32x4 r1 = *(const f32x4*)&partials[pbase + KK + t * 8 + 4];
    f32x4 i0 = *(const f32x4*)&partials[pbase + KK + FLAT + t * 8];
    f32x4 i1 = *(const f32x4*)&partials[pbase + KK + FLAT + t * 8 + 4];
    float rs[8] = {r0[0], r0[1], r0[2], r0[3], r1[0], r1[1], r1[2], r1[3]};
    float is[8] = {i0[0], i0[1], i0[2], i0[3], i1[0], i1[1], i1[2], i1[3]};
    float den = partials[pbase + k];

#pragma unroll 1
    for (int i = 0; i < CH; ++i) {
        float kv = b2f(zin[i][t]) * cz0 + b2f(zin[i + 1][t]) * cz1 +
                   b2f(zin[i + 2][t]) * cz2 + b2f(zin[i + 3][t]) * cz3;
        float s = b2f(zin[i][sc]) * cs0 + b2f(zin[i + 1][sc]) * cs1 +
                  b2f(zin[i + 2][sc]) * cs2 + b2f(zin[i + 3][sc]) * cs3;
        int l = l0 + i;
        float lw = (k < KK - 4) ? -sp * (float)(LL - 1 - l) : -sp * (float)l;
        float lp = fminf(fmaxf(ss * s, -20.f), 20.f);
        float p = __expf(lp + lw);
        den += p;
        float inv = __builtin_amdgcn_rcpf(fmaxf(den, 1e-4f));
#pragma unroll
        for (int m = 0; m < 8; ++m) {
            float sn, cn;
            __sincosf(kv * th[m], &sn, &cn);
            rs[m] += p * cn;
            is[m] += p * sn;
        }
        u16x8 qv0 = *(const u16x8*)&qall[i][qb];
        u16x8 qv1 = *(const u16x8*)&qall[i][qb + 8];
        float o_re = 0.f, o_im = 0.f;
#pragma unroll
        for (int m = 0; m < 8; ++m) {
            float sre = rs[m] * inv;
            float sim = is[m] * inv;
            float qre = b2f((unsigned short)((m < 4) ? qv0[2 * m] : qv1[2 * m - 8]));
            float qim = b2f((unsigned short)((m < 4) ? qv0[2 * m + 1] : qv1[2 * m - 7]));
            o_re += sre * qre + sim * qim;
            o_im += sim * qre - sre * qim;
        }
        o_re *= ns;
        o_im *= ns;

        float y0 = 0.f, y1 = 0.f, y2 = 0.f, y3 = 0.f, y4 = 0.f, y5 = 0.f;
#define EAPPLY(HH) { float br_ = bcast8<HH>(o_re); float bi_ = bcast8<HH>(o_im); \
        y0 += br_ * wre[HH][0] + bi_ * wim[HH][0]; \
        y1 += br_ * wre[HH][1] + bi_ * wim[HH][1]; \
        y2 += br_ * wre[HH][2] + bi_ * wim[HH][2]; \
        y3 += br_ * wre[HH][3] + bi_ * wim[HH][3]; \
        y4 += br_ * wre[HH][4] + bi_ * wim[HH][4]; \
        y5 += br_ * wre[HH][5] + bi_ * wim[HH][5]; }
        EAPPLY(0) EAPPLY(1) EAPPLY(2) EAPPLY(3)
        EAPPLY(4) EAPPLY(5) EAPPLY(6) EAPPLY(7)
#undef EAPPLY

        size_t ybase = (size_t)(b * LL + l) * YDIM + k * 24 + h;
        y_act[ybase]      = f2b(fast_sigmoid_mul(y0 * y3, y3));
        y_act[ybase + 8]  = f2b(fast_sigmoid_mul(y1 * y4, y4));
        y_act[ybase + 16] = f2b(fast_sigmoid_mul(y2 * y5, y5));
    }
}

extern "C" void kernel_launch(void* const* d_in, const int* in_sizes, int n_in,
                              void* d_out, int out_size, void* d_ws, size_t ws_size,
                              hipStream_t stream) {
    const float* x      = (const float*)d_in[0];
    const float* W_mem  = (const float*)d_in[1];
    const float* conv_k = (const float*)d_in[2];
    const float* W_q    = (const float*)d_in[3];
    const float* theta  = (const float*)d_in[4];
    const float* decay  = (const float*)d_in[5];
    const float* anchor = (const float*)d_in[6];
    const float* sscale = (const float*)d_in[7];
    const float* W_re   = (const float*)d_in[8];
    const float* W_im   = (const float*)d_in[9];
    const float* nscale = (const float*)d_in[10];
    const float* W_out  = (const float*)d_in[11];
    float* out = (float*)d_out;
    float* ws = (float*)d_ws;

    // ---- d_out stash (dead before final GEMM writes d_out) ----
    unsigned short* Wb = (unsigned short*)out;                 // 896*2048 bf16 = 917,504 float slots
    unsigned short* zq = (unsigned short*)(out + 917504);      // 8192*800 bf16 = 3,276,800 slots, ends 4,194,304
    // ---- ws (offsets in float slots) ----
    float* partials      = ws;                                 // 2*256*4128 = 2,113,536 floats
    unsigned short* yb   = (unsigned short*)(ws + 2113536);    // 8192*768 bf16 = 3,145,728 float slots
    unsigned short* Wo   = (unsigned short*)(ws + 5259264);    // 2048*768 bf16 = 786,432 float slots
                                                               // ends 6,045,696 floats (24.2 MB)

    prep_wb<<<NPAD, 256, 0, stream>>>(W_mem, W_q, Wb);
    prep_wo<<<DD, 256, 0, stream>>>(W_out, Wo);

    // 1) zq = x @ [W_mem | W_q]   (8192 x 800 x 2048), f32 A reg-staged + converted in-kernel
    gemm_zq<<<dim3(NPAD / 128, BL / 128), 256, 0, stream>>>(
        x, Wb, zq, DD, ZSTR, ZSTR);
    // 2) chunk partial sums (conv+trig recompute, registers only)
    fused_partial<<<dim3(NCH, BB), 256, 0, stream>>>(zq, conv_k, theta, decay, anchor, sscale, partials);
    // 3) exclusive scan of chunk partials
    scan_partials<<<dim3(CMERG / 16, BB), 256, 0, stream>>>(partials);
    // 4) recompute + in-register inclusive scan + fused stage_d -> y (bf16)
    fused_stage<<<dim3(NCH, BB), 256, 0, stream>>>(zq, conv_k, theta, decay, anchor, sscale,
                                                   partials, W_re, W_im, nscale, yb);
    // 5) out = y @ Wo^T  (8192 x 2048 x 768), single-bf16 B
    gemm256<<<dim3(DD / 256, BL / 256), 512, 0, stream>>>(yb, Wo, out, YDIM, DD);
}

// Round 17
// 155.609 us; speedup vs baseline: 1.0383x; 1.0383x over previous
//
#include <hip/hip_runtime.h>
#include <hip/hip_bf16.h>
#include <math.h>

// Problem constants
#define BB 2
#define LL 4096
#define DD 2048
#define KK 32
#define MEM 256          // K*H
#define CTOT 288         // MEM+K
#define NQ 512           // KQ*H*M*2
#define ZSTR 800         // CTOT + NQ (combined z|q GEMM output stride)
#define NPAD 896         // padded N for combined GEMM (7*128)
#define FLAT 2048        // K*H*M
#define CMERG 4128       // K + 2*FLAT
#define CH 16            // scan chunk length
#define NCH 256          // L / CH
#define YDIM 768         // K*24
#define BL (BB*LL)       // 8192

typedef __attribute__((ext_vector_type(4))) float f32x4;
typedef __attribute__((ext_vector_type(8))) short bf16x8;
typedef __attribute__((ext_vector_type(8))) unsigned short u16x8;

__device__ inline unsigned short f2b(float v) {
    __hip_bfloat16 h = __float2bfloat16(v);
    return *reinterpret_cast<unsigned short*>(&h);
}
__device__ inline float b2f(unsigned short u) {
    __hip_bfloat16 h;
    *reinterpret_cast<unsigned short*>(&h) = u;
    return __bfloat162float(h);
}

__device__ inline void gload16(const void* g, void* l) {
    __builtin_amdgcn_global_load_lds(
        (const __attribute__((address_space(1))) unsigned int*)g,
        (__attribute__((address_space(3))) unsigned int*)l, 16, 0, 0);
}

// vmcnt ladder for gemm256's 4-buffer pipeline (4 loads per stage)
__device__ inline void wait_stage(int it, int nIter) {
    if (it + 3 <= nIter) asm volatile("s_waitcnt vmcnt(8)" ::: "memory");
    else if (it + 2 == nIter) asm volatile("s_waitcnt vmcnt(4)" ::: "memory");
    else asm volatile("s_waitcnt vmcnt(0)" ::: "memory");
}

// broadcast lane (group_base | HH) within aligned 8-lane groups (BitMode swizzle)
template<int HH>
__device__ inline float bcast8(float v) {
    return __int_as_float(__builtin_amdgcn_ds_swizzle(__float_as_int(v), (HH << 5) | 0x18));
}

__device__ inline float fast_sigmoid_mul(float val, float g) {
    return val * __builtin_amdgcn_rcpf(1.f + __expf(-g));
}

// ---------------- weight preps ----------------
__global__ __launch_bounds__(256) void prep_wb(const float* __restrict__ W_mem,
                                               const float* __restrict__ W_q,
                                               unsigned short* __restrict__ Wb) {
    int n = blockIdx.x;   // 0..895
    for (int k = threadIdx.x; k < DD; k += 256) {
        float v = 0.f;
        if (n < CTOT) v = W_mem[(size_t)k * CTOT + n];
        else if (n < ZSTR) v = W_q[(size_t)k * NQ + (n - CTOT)];
        Wb[(size_t)n * DD + k] = f2b(v);
    }
}

// W_out^T as [N=2048][K=768] bf16
__global__ __launch_bounds__(256) void prep_wo(const float* __restrict__ W_out,
                                               unsigned short* __restrict__ Wo) {
    int n = blockIdx.x;   // 0..2047
    for (int k = threadIdx.x; k < YDIM; k += 256) {
        Wo[(size_t)n * YDIM + k] = f2b(W_out[(size_t)k * DD + n]);
    }
}

// ---------------- 128x128 MFMA GEMM (zq), A = f32 in HBM via E/O split tile ----------------
// A-tile split: E[128][4 slots] holds floats 0-3 of each 8-k-group, O holds floats 4-7.
// Each has 64B rows, swizzle s^((row>>1)&3) -> per-instruction bank pattern identical to the
// measured-0-conflict bf16 tile. Staged by global_load_lds (source-permuted). B unchanged.
__global__ __launch_bounds__(256) void gemm_zq(const float* __restrict__ Af,
                                               const unsigned short* __restrict__ Bh_g,
                                               unsigned short* __restrict__ Cout,
                                               int Kd, int Nvalid, int Cstride) {
    __shared__ __attribute__((aligned(16))) float As[2][4096];          // [E 2048 | O 2048] f32
    __shared__ __attribute__((aligned(16))) unsigned short Bh[2][4096]; // 128 x 32 bf16
    int tid = threadIdx.x;
    int lane = tid & 63;
    int wave = tid >> 6;
    int wr = wave >> 1, wc = wave & 1;

    int nwg = gridDim.x * gridDim.y;
    int bid = blockIdx.y * gridDim.x + blockIdx.x;
    int cpx = nwg >> 3;
    int swz = (bid & 7) * cpx + (bid >> 3);
    int bx = swz % gridDim.x, by = swz / gridDim.x;
    int m0 = by * 128;
    int n0 = bx * 128;

    f32x4 acc[4][4];
#pragma unroll
    for (int i = 0; i < 4; ++i)
#pragma unroll
        for (int j = 0; j < 4; ++j) acc[i][j] = (f32x4){0.f, 0.f, 0.f, 0.f};

    // A staging: 1024 16B-slots; f = tile*512 + row*4 + sp; source col = (sp^x2)*8 + tile*4
    const float* pA[4];
    int offA[4];
#pragma unroll
    for (int j = 0; j < 4; ++j) {
        int f = j * 256 + tid;
        int tile = f >> 9, rem = f & 511;
        int row = rem >> 2, sp = rem & 3;
        int sl = sp ^ ((row >> 1) & 3);
        pA[j] = Af + (size_t)(m0 + row) * Kd + sl * 8 + tile * 4;
        offA[j] = f * 4;
    }
    // B staging: 512 slots, 2 per thread; slot swizzle s ^ ((row>>1)&3)
    const unsigned short* pB[2];
    int offB[2];
#pragma unroll
    for (int j = 0; j < 2; ++j) {
        int f = j * 256 + tid;
        int row = f >> 2, s = f & 3;
        int sg = s ^ ((row >> 1) & 3);
        pB[j] = Bh_g + (size_t)(n0 + row) * Kd + sg * 8;
        offB[j] = f * 8;
    }

    int g = lane >> 4, rr = lane & 15;

#define STAGE(buf, k0) do {                                            \
        gload16(pA[0] + (k0), &As[buf][offA[0]]);                      \
        gload16(pA[1] + (k0), &As[buf][offA[1]]);                      \
        gload16(pA[2] + (k0), &As[buf][offA[2]]);                      \
        gload16(pA[3] + (k0), &As[buf][offA[3]]);                      \
        gload16(pB[0] + (k0), &Bh[buf][offB[0]]);                      \
        gload16(pB[1] + (k0), &Bh[buf][offB[1]]);                      \
    } while (0)

    STAGE(0, 0);
    __syncthreads();

    int nIter = Kd >> 5;    // 64
    int cur = 0;
    for (int it = 0; it < nIter; ++it) {
        if (it + 1 < nIter) STAGE(cur ^ 1, (it + 1) * 32);

        bf16x8 av[4], bhv[4];
#pragma unroll
        for (int i = 0; i < 4; ++i) {
            int ra = wr * 64 + i * 16 + rr;
            int sl = (g ^ ((ra >> 1) & 3)) * 4;
            f32x4 alo = *(const f32x4*)&As[cur][ra * 16 + sl];           // E tile
            f32x4 ahi = *(const f32x4*)&As[cur][2048 + ra * 16 + sl];    // O tile
            u16x8 ua;
            ua[0] = f2b(alo[0]); ua[1] = f2b(alo[1]); ua[2] = f2b(alo[2]); ua[3] = f2b(alo[3]);
            ua[4] = f2b(ahi[0]); ua[5] = f2b(ahi[1]); ua[6] = f2b(ahi[2]); ua[7] = f2b(ahi[3]);
            av[i] = *(bf16x8*)&ua;
            int rb = wc * 64 + i * 16 + rr;
            bhv[i] = *(const bf16x8*)&Bh[cur][rb * 32 + ((g ^ ((rb >> 1) & 3)) * 8)];
        }
#pragma unroll
        for (int i = 0; i < 4; ++i)
#pragma unroll
            for (int j = 0; j < 4; ++j)
                acc[i][j] = __builtin_amdgcn_mfma_f32_16x16x32_bf16(av[i], bhv[j], acc[i][j], 0, 0, 0);

        __syncthreads();
        cur ^= 1;
    }
#undef STAGE

    int cg = lane >> 4, cr = lane & 15;
#pragma unroll
    for (int i = 0; i < 4; ++i)
#pragma unroll
        for (int j = 0; j < 4; ++j) {
            int colb = n0 + wc * 64 + j * 16 + cr;
            if (colb < Nvalid) {
#pragma unroll
                for (int r = 0; r < 4; ++r) {
                    int rowb = m0 + wr * 64 + i * 16 + cg * 4 + r;
                    Cout[(size_t)rowb * Cstride + colb] = f2b(acc[i][j][r]);
                }
            }
        }
}

// ---------------- 256x256 8-wave GEMM (final), BK=32, 4-buffer distance-2 pipeline ----------------
__global__ __launch_bounds__(512, 2) void gemm256(const unsigned short* __restrict__ A,
                                                  const unsigned short* __restrict__ Bm,
                                                  float* __restrict__ C,
                                                  int Kd, int Cstride) {
    __shared__ __attribute__((aligned(16))) unsigned short As[4][8192];
    __shared__ __attribute__((aligned(16))) unsigned short Bs[4][8192];
    int tid = threadIdx.x;
    int lane = tid & 63, wave = tid >> 6;
    int wm = wave >> 2, wn = wave & 3;

    int nwg = gridDim.x * gridDim.y;            // 256
    int bid = blockIdx.y * gridDim.x + blockIdx.x;
    int cpx = nwg >> 3;
    int swz = (bid & 7) * cpx + (bid >> 3);
    int bx = swz % gridDim.x, by = swz / gridDim.x;
    int m0 = by * 256, n0 = bx * 256;

    f32x4 acc[8][4];
#pragma unroll
    for (int i = 0; i < 8; ++i)
#pragma unroll
        for (int j = 0; j < 4; ++j) acc[i][j] = (f32x4){0.f, 0.f, 0.f, 0.f};

    const unsigned short* pA[2];
    const unsigned short* pB[2];
    int ldsoff[2];
#pragma unroll
    for (int j = 0; j < 2; ++j) {
        int f = j * 512 + tid;
        int row = f >> 2, s = f & 3;
        int sg = s ^ ((row >> 1) & 3);
        pA[j] = A + (size_t)(m0 + row) * Kd + sg * 8;
        pB[j] = Bm + (size_t)(n0 + row) * Kd + sg * 8;
        ldsoff[j] = (j * 512 + wave * 64) * 8;
    }

    int rr = lane & 15, kg = lane >> 4;

#define STAGE(buf, koff) do {                                          \
        gload16(pA[0] + (koff), &As[buf][ldsoff[0]]);                  \
        gload16(pA[1] + (koff), &As[buf][ldsoff[1]]);                  \
        gload16(pB[0] + (koff), &Bs[buf][ldsoff[0]]);                  \
        gload16(pB[1] + (koff), &Bs[buf][ldsoff[1]]);                  \
    } while (0)

    int nT = Kd >> 5;       // 24
    STAGE(0, 0);
    STAGE(1, 32);

#define LDA(fr) ({ int ra_ = wm * 128 + (fr) * 16 + rr;                          \
        *(const bf16x8*)&As[cur][ra_ * 32 + ((kg ^ ((ra_ >> 1) & 3)) * 8)]; })
#define LDB(fc) ({ int rb_ = wn * 64 + (fc) * 16 + rr;                           \
        *(const bf16x8*)&Bs[cur][rb_ * 32 + ((kg ^ ((rb_ >> 1) & 3)) * 8)]; })

    for (int it = 0; it < nT; ++it) {
        int cur = it & 3;
        if (it + 2 < nT) STAGE((it + 2) & 3, (it + 2) * 32);
        wait_stage(it, nT);
        __builtin_amdgcn_s_barrier();

        bf16x8 bv[4];
#pragma unroll
        for (int j = 0; j < 4; ++j) bv[j] = LDB(j);
#pragma unroll
        for (int i = 0; i < 8; ++i) {
            bf16x8 a0 = LDA(i);
#pragma unroll
            for (int j = 0; j < 4; ++j)
                acc[i][j] = __builtin_amdgcn_mfma_f32_16x16x32_bf16(a0, bv[j], acc[i][j], 0, 0, 0);
        }
    }
#undef LDA
#undef LDB
#undef STAGE

    int cg = lane >> 4;
#pragma unroll
    for (int i = 0; i < 8; ++i)
#pragma unroll
        for (int j = 0; j < 4; ++j) {
            int colb = n0 + wn * 64 + j * 16 + rr;
#pragma unroll
            for (int r = 0; r < 4; ++r) {
                int rowb = m0 + wm * 128 + i * 16 + cg * 4 + r;
                C[(size_t)rowb * Cstride + colb] = acc[i][j][r];
            }
        }
}

// ---------------- fused A: conv+trig chunk partial sums ----------------
__global__ __launch_bounds__(256) void fused_partial(const unsigned short* __restrict__ zq,
                                                     const float* __restrict__ conv_k,
                                                     const float* __restrict__ theta,
                                                     const float* __restrict__ decay,
                                                     const float* __restrict__ anchor,
                                                     const float* __restrict__ sscale,
                                                     float* __restrict__ partials) {
    int chunk = blockIdx.x, b = blockIdx.y, t = threadIdx.x;
    int l0 = chunk * CH;
    __shared__ unsigned short zin[CH + 3][CTOT];

    for (int idx = t; idx < (CH + 3) * 36; idx += 256) {
        int r = idx / 36, c8 = (idx % 36) * 8;
        int l = l0 - 3 + r;
        u16x8 v = (u16x8)(0);
        if (l >= 0) v = *(const u16x8*)&zq[(size_t)(b * LL + l) * ZSTR + c8];
        *(u16x8*)&zin[r][c8] = v;
    }
    __syncthreads();

    int k = t >> 3;
    float cz0 = conv_k[t], cz1 = conv_k[CTOT + t], cz2 = conv_k[2 * CTOT + t], cz3 = conv_k[3 * CTOT + t];
    int sc = MEM + k;
    float cs0 = conv_k[sc], cs1 = conv_k[CTOT + sc], cs2 = conv_k[2 * CTOT + sc], cs3 = conv_k[3 * CTOT + sc];
    float xx = (k < KK - 4) ? decay[k] : anchor[k - (KK - 4)];
    float sp = (xx > 20.f) ? xx : log1pf(__expf(xx));
    float ss = sscale[k];
    float th[8];
#pragma unroll
    for (int m = 0; m < 8; ++m) th[m] = theta[t * 8 + m];
    float rs[8], is[8];
#pragma unroll
    for (int m = 0; m < 8; ++m) { rs[m] = 0.f; is[m] = 0.f; }
    float dsum = 0.f;

#pragma unroll 1
    for (int i = 0; i < CH; ++i) {
        float kv = b2f(zin[i][t]) * cz0 + b2f(zin[i + 1][t]) * cz1 +
                   b2f(zin[i + 2][t]) * cz2 + b2f(zin[i + 3][t]) * cz3;
        float s = b2f(zin[i][sc]) * cs0 + b2f(zin[i + 1][sc]) * cs1 +
                  b2f(zin[i + 2][sc]) * cs2 + b2f(zin[i + 3][sc]) * cs3;
        int l = l0 + i;
        float lw = (k < KK - 4) ? -sp * (float)(LL - 1 - l) : -sp * (float)l;
        float lp = fminf(fmaxf(ss * s, -20.f), 20.f);
        float p = __expf(lp + lw);
        dsum += p;
#pragma unroll
        for (int m = 0; m < 8; ++m) {
            float sn, cn;
            __sincosf(kv * th[m], &sn, &cn);
            rs[m] += p * cn;
            is[m] += p * sn;
        }
    }
    size_t base = ((size_t)b * NCH + chunk) * CMERG;
    *(f32x4*)&partials[base + KK + t * 8]            = (f32x4){rs[0], rs[1], rs[2], rs[3]};
    *(f32x4*)&partials[base + KK + t * 8 + 4]        = (f32x4){rs[4], rs[5], rs[6], rs[7]};
    *(f32x4*)&partials[base + KK + FLAT + t * 8]     = (f32x4){is[0], is[1], is[2], is[3]};
    *(f32x4*)&partials[base + KK + FLAT + t * 8 + 4] = (f32x4){is[4], is[5], is[6], is[7]};
    if ((t & 7) == 0) partials[base + k] = dsum;
}

// ---------------- fused B: exclusive scan of chunk partials (in place) ----------------
__global__ __launch_bounds__(256) void scan_partials(float* __restrict__ partials) {
    int t = threadIdx.x;
    int cl = t & 15, j = t >> 4;
    int c = blockIdx.x * 16 + cl;
    int b = blockIdx.y;
    float v[16];
    float s = 0.f;
#pragma unroll
    for (int i = 0; i < 16; ++i) {
        v[i] = partials[((size_t)b * NCH + j * 16 + i) * CMERG + c];
        s += v[i];
    }
    __shared__ float sums[16][17];
    sums[j][cl] = s;
    __syncthreads();
    if (j == 0) {
        float run = 0.f;
#pragma unroll
        for (int jj = 0; jj < 16; ++jj) {
            float x = sums[jj][cl];
            sums[jj][cl] = run;
            run += x;
        }
    }
    __syncthreads();
    float run = sums[j][cl];
#pragma unroll
    for (int i = 0; i < 16; ++i) {
        float x = v[i];
        partials[((size_t)b * NCH + j * 16 + i) * CMERG + c] = run;
        run += x;
    }
}

// ---------------- fused C: recompute + in-register scan + stage_d ----------------
__global__ __launch_bounds__(256) void fused_stage(const unsigned short* __restrict__ zq,
                                                   const float* __restrict__ conv_k,
                                                   const float* __restrict__ theta,
                                                   const float* __restrict__ decay,
                                                   const float* __restrict__ anchor,
                                                   const float* __restrict__ sscale,
                                                   const float* __restrict__ partials,
                                                   const float* __restrict__ W_re,
                                                   const float* __restrict__ W_im,
                                                   const float* __restrict__ nscale,
                                                   unsigned short* __restrict__ y_act) {
    int chunk = blockIdx.x, b = blockIdx.y, t = threadIdx.x;
    int l0 = chunk * CH;
    __shared__ unsigned short zin[CH + 3][CTOT];
    __shared__ unsigned short qall[CH][NQ];

    for (int idx = t; idx < (CH + 3) * 36; idx += 256) {
        int r = idx / 36, c8 = (idx % 36) * 8;
        int l = l0 - 3 + r;
        u16x8 v = (u16x8)(0);
        if (l >= 0) v = *(const u16x8*)&zq[(size_t)(b * LL + l) * ZSTR + c8];
        *(u16x8*)&zin[r][c8] = v;
    }
    for (int idx = t; idx < CH * (NQ / 8); idx += 256) {
        int i = idx >> 6, c8 = (idx & 63) * 8;
        *(u16x8*)&qall[i][c8] = *(const u16x8*)&zq[(size_t)(b * LL + l0 + i) * ZSTR + CTOT + c8];
    }
    __syncthreads();

    int k = t >> 3, h = t & 7, w = t >> 6;
    float cz0 = conv_k[t], cz1 = conv_k[CTOT + t], cz2 = conv_k[2 * CTOT + t], cz3 = conv_k[3 * CTOT + t];
    int sc = MEM + k;
    float cs0 = conv_k[sc], cs1 = conv_k[CTOT + sc], cs2 = conv_k[2 * CTOT + sc], cs3 = conv_k[3 * CTOT + sc];
    float xx = (k < KK - 4) ? decay[k] : anchor[k - (KK - 4)];
    float sp = (xx > 20.f) ? xx : log1pf(__expf(xx));
    float ss = sscale[k];
    float th[8];
#pragma unroll
    for (int m = 0; m < 8; ++m) th[m] = theta[t * 8 + m];
    float ns = nscale[t];
    int qb = w * 128 + h * 16;

    float wre[8][6], wim[8][6];
#pragma unroll
    for (int hh = 0; hh < 8; ++hh)
#pragma unroll
        for (int jj = 0; jj < 6; ++jj) {
            wre[hh][jj] = W_re[(k * 8 + hh) * 48 + h + 8 * jj];
            wim[hh][jj] = W_im[(k * 8 + hh) * 48 + h + 8 * jj];
        }

    size_t pbase = ((size_t)b * NCH + chunk) * CMERG;
    f32x4 r0 = *(const f32x4*)&partials[pbase + KK + t * 8];
    f32x4 r1 = *(const f32x4*)&partials[pbase + KK + t * 8 + 4];
    f32x4 i0 = *(const f32x4*)&partials[pbase + KK + FLAT + t * 8];
    f32x4 i1 = *(const f32x4*)&partials[pbase + KK + FLAT + t * 8 + 4];
    float rs[8] = {r0[0], r0[1], r0[2], r0[3], r1[0], r1[1], r1[2], r1[3]};
    float is[8] = {i0[0], i0[1], i0[2], i0[3], i1[0], i1[1], i1[2], i1[3]};
    float den = partials[pbase + k];

#pragma unroll 1
    for (int i = 0; i < CH; ++i) {
        float kv = b2f(zin[i][t]) * cz0 + b2f(zin[i + 1][t]) * cz1 +
                   b2f(zin[i + 2][t]) * cz2 + b2f(zin[i + 3][t]) * cz3;
        float s = b2f(zin[i][sc]) * cs0 + b2f(zin[i + 1][sc]) * cs1 +
                  b2f(zin[i + 2][sc]) * cs2 + b2f(zin[i + 3][sc]) * cs3;
        int l = l0 + i;
        float lw = (k < KK - 4) ? -sp * (float)(LL - 1 - l) : -sp * (float)l;
        float lp = fminf(fmaxf(ss * s, -20.f), 20.f);
        float p = __expf(lp + lw);
        den += p;
        float inv = __builtin_amdgcn_rcpf(fmaxf(den, 1e-4f));
#pragma unroll
        for (int m = 0; m < 8; ++m) {
            float sn, cn;
            __sincosf(kv * th[m], &sn, &cn);
            rs[m] += p * cn;
            is[m] += p * sn;
        }
        u16x8 qv0 = *(const u16x8*)&qall[i][qb];
        u16x8 qv1 = *(const u16x8*)&qall[i][qb + 8];
        float o_re = 0.f, o_im = 0.f;
#pragma unroll
        for (int m = 0; m < 8; ++m) {
            float sre = rs[m] * inv;
            float sim = is[m] * inv;
            float qre = b2f((unsigned short)((m < 4) ? qv0[2 * m] : qv1[2 * m - 8]));
            float qim = b2f((unsigned short)((m < 4) ? qv0[2 * m + 1] : qv1[2 * m - 7]));
            o_re += sre * qre + sim * qim;
            o_im += sim * qre - sre * qim;
        }
        o_re *= ns;
        o_im *= ns;

        float y0 = 0.f, y1 = 0.f, y2 = 0.f, y3 = 0.f, y4 = 0.f, y5 = 0.f;
#define EAPPLY(HH) { float br_ = bcast8<HH>(o_re); float bi_ = bcast8<HH>(o_im); \
        y0 += br_ * wre[HH][0] + bi_ * wim[HH][0]; \
        y1 += br_ * wre[HH][1] + bi_ * wim[HH][1]; \
        y2 += br_ * wre[HH][2] + bi_ * wim[HH][2]; \
        y3 += br_ * wre[HH][3] + bi_ * wim[HH][3]; \
        y4 += br_ * wre[HH][4] + bi_ * wim[HH][4]; \
        y5 += br_ * wre[HH][5] + bi_ * wim[HH][5]; }
        EAPPLY(0) EAPPLY(1) EAPPLY(2) EAPPLY(3)
        EAPPLY(4) EAPPLY(5) EAPPLY(6) EAPPLY(7)
#undef EAPPLY

        size_t ybase = (size_t)(b * LL + l) * YDIM + k * 24 + h;
        y_act[ybase]      = f2b(fast_sigmoid_mul(y0 * y3, y3));
        y_act[ybase + 8]  = f2b(fast_sigmoid_mul(y1 * y4, y4));
        y_act[ybase + 16] = f2b(fast_sigmoid_mul(y2 * y5, y5));
    }
}

extern "C" void kernel_launch(void* const* d_in, const int* in_sizes, int n_in,
                              void* d_out, int out_size, void* d_ws, size_t ws_size,
                              hipStream_t stream) {
    const float* x      = (const float*)d_in[0];
    const float* W_mem  = (const float*)d_in[1];
    const float* conv_k = (const float*)d_in[2];
    const float* W_q    = (const float*)d_in[3];
    const float* theta  = (const float*)d_in[4];
    const float* decay  = (const float*)d_in[5];
    const float* anchor = (const float*)d_in[6];
    const float* sscale = (const float*)d_in[7];
    const float* W_re   = (const float*)d_in[8];
    const float* W_im   = (const float*)d_in[9];
    const float* nscale = (const float*)d_in[10];
    const float* W_out  = (const float*)d_in[11];
    float* out = (float*)d_out;
    float* ws = (float*)d_ws;

    // ---- d_out stash (dead before final GEMM writes d_out) ----
    unsigned short* Wb = (unsigned short*)out;                 // 896*2048 bf16 = 917,504 float slots
    unsigned short* zq = (unsigned short*)(out + 917504);      // 8192*800 bf16 = 3,276,800 slots, ends 4,194,304
    // ---- ws (offsets in float slots) ----
    float* partials      = ws;                                 // 2*256*4128 = 2,113,536 floats
    unsigned short* yb   = (unsigned short*)(ws + 2113536);    // 8192*768 bf16 = 3,145,728 float slots
    unsigned short* Wo   = (unsigned short*)(ws + 5259264);    // 2048*768 bf16 = 786,432 float slots
                                                               // ends 6,045,696 floats (24.2 MB)

    prep_wb<<<NPAD, 256, 0, stream>>>(W_mem, W_q, Wb);
    prep_wo<<<DD, 256, 0, stream>>>(W_out, Wo);

    // 1) zq = x @ [W_mem | W_q]   (8192 x 800 x 2048), f32 A staged via E/O split tile
    gemm_zq<<<dim3(NPAD / 128, BL / 128), 256, 0, stream>>>(
        x, Wb, zq, DD, ZSTR, ZSTR);
    // 2) chunk partial sums (conv+trig recompute, registers only)
    fused_partial<<<dim3(NCH, BB), 256, 0, stream>>>(zq, conv_k, theta, decay, anchor, sscale, partials);
    // 3) exclusive scan of chunk partials
    scan_partials<<<dim3(CMERG / 16, BB), 256, 0, stream>>>(partials);
    // 4) recompute + in-register inclusive scan + fused stage_d -> y (bf16)
    fused_stage<<<dim3(NCH, BB), 256, 0, stream>>>(zq, conv_k, theta, decay, anchor, sscale,
                                                   partials, W_re, W_im, nscale, yb);
    // 5) out = y @ Wo^T  (8192 x 2048 x 768), single-bf16 B
    gemm256<<<dim3(DD / 256, BL / 256), 512, 0, stream>>>(yb, Wo, out, YDIM, DD);
}

// Round 19
// 154.478 us; speedup vs baseline: 1.0459x; 1.0073x over previous
//
#include <hip/hip_runtime.h>
#include <hip/hip_bf16.h>
#include <math.h>

// Problem constants
#define BB 2
#define LL 4096
#define DD 2048
#define KK 32
#define MEM 256          // K*H
#define CTOT 288         // MEM+K
#define NQ 512           // KQ*H*M*2
#define ZSTR 800         // CTOT + NQ (combined z|q GEMM output stride)
#define NPAD 896         // padded N for combined GEMM (7*128)
#define FLAT 2048        // K*H*M
#define CMERG 4128       // K + 2*FLAT
#define CH 16            // scan chunk length
#define NCH 256          // L / CH
#define YDIM 768         // K*24
#define BL (BB*LL)       // 8192

typedef __attribute__((ext_vector_type(4))) float f32x4;
typedef __attribute__((ext_vector_type(8))) short bf16x8;
typedef __attribute__((ext_vector_type(8))) unsigned short u16x8;

__device__ inline unsigned short f2b(float v) {
    __hip_bfloat16 h = __float2bfloat16(v);
    return *reinterpret_cast<unsigned short*>(&h);
}
__device__ inline float b2f(unsigned short u) {
    __hip_bfloat16 h;
    *reinterpret_cast<unsigned short*>(&h) = u;
    return __bfloat162float(h);
}

__device__ inline void gload16(const void* g, void* l) {
    __builtin_amdgcn_global_load_lds(
        (const __attribute__((address_space(1))) unsigned int*)g,
        (__attribute__((address_space(3))) unsigned int*)l, 16, 0, 0);
}

// vmcnt ladder for 4-deep pipelines (4 loads per stage)
__device__ inline void wait_stage(int it, int nIter) {
    if (it + 3 <= nIter) asm volatile("s_waitcnt vmcnt(8)" ::: "memory");
    else if (it + 2 == nIter) asm volatile("s_waitcnt vmcnt(4)" ::: "memory");
    else asm volatile("s_waitcnt vmcnt(0)" ::: "memory");
}

// broadcast lane (group_base | HH) within aligned 8-lane groups (BitMode swizzle)
template<int HH>
__device__ inline float bcast8(float v) {
    return __int_as_float(__builtin_amdgcn_ds_swizzle(__float_as_int(v), (HH << 5) | 0x18));
}

__device__ inline float fast_sigmoid_mul(float val, float g) {
    return val * __builtin_amdgcn_rcpf(1.f + __expf(-g));
}

// ---------------- weight preps ----------------
__global__ __launch_bounds__(256) void prep_wb(const float* __restrict__ W_mem,
                                               const float* __restrict__ W_q,
                                               unsigned short* __restrict__ Wb) {
    int n = blockIdx.x;   // 0..895
    for (int k = threadIdx.x; k < DD; k += 256) {
        float v = 0.f;
        if (n < CTOT) v = W_mem[(size_t)k * CTOT + n];
        else if (n < ZSTR) v = W_q[(size_t)k * NQ + (n - CTOT)];
        Wb[(size_t)n * DD + k] = f2b(v);
    }
}

// W_out^T as [N=2048][K=768] bf16
__global__ __launch_bounds__(256) void prep_wo(const float* __restrict__ W_out,
                                               unsigned short* __restrict__ Wo) {
    int n = blockIdx.x;   // 0..2047
    for (int k = threadIdx.x; k < YDIM; k += 256) {
        Wo[(size_t)n * YDIM + k] = f2b(W_out[(size_t)k * DD + n]);
    }
}

// ---------------- 128x128 MFMA GEMM (zq), A = f32 in HBM, converted in-register ----------------
// A staged as f32 via global_load_lds (8 slots/row, swizzle s^(row&7));
// fragments read as 2x ds_read_b128 f32 then cvt->bf16 (bit-identical to cvt_x+bf16 path).
// B = bf16, proven layout/swizzle. 2-buffer, round-12 schedule.
__global__ __launch_bounds__(256) void gemm_zq(const float* __restrict__ Af,
                                               const unsigned short* __restrict__ Bh_g,
                                               unsigned short* __restrict__ Cout,
                                               int Kd, int Nvalid, int Cstride) {
    __shared__ __attribute__((aligned(16))) float As[2][4096];          // 128 x 32 f32 = 16 KB
    __shared__ __attribute__((aligned(16))) unsigned short Bh[2][4096]; // 128 x 32 bf16 = 8 KB
    int tid = threadIdx.x;
    int lane = tid & 63;
    int wave = tid >> 6;
    int wr = wave >> 1, wc = wave & 1;

    int nwg = gridDim.x * gridDim.y;
    int bid = blockIdx.y * gridDim.x + blockIdx.x;
    int cpx = nwg >> 3;
    int swz = (bid & 7) * cpx + (bid >> 3);
    int bx = swz % gridDim.x, by = swz / gridDim.x;
    int m0 = by * 128;
    int n0 = bx * 128;

    f32x4 acc[4][4];
#pragma unroll
    for (int i = 0; i < 4; ++i)
#pragma unroll
        for (int j = 0; j < 4; ++j) acc[i][j] = (f32x4){0.f, 0.f, 0.f, 0.f};

    // A staging: 1024 slots (16B), 4 per thread; slot swizzle s ^ (row&7)
    const float* pA[4];
    int offA[4];
#pragma unroll
    for (int j = 0; j < 4; ++j) {
        int f = j * 256 + tid;
        int row = f >> 3, s = f & 7;
        int sg = s ^ (row & 7);
        pA[j] = Af + (size_t)(m0 + row) * Kd + sg * 4;
        offA[j] = f * 4;
    }
    // B staging: 512 slots, 2 per thread; slot swizzle s ^ ((row>>1)&3)
    const unsigned short* pB[2];
    int offB[2];
#pragma unroll
    for (int j = 0; j < 2; ++j) {
        int f = j * 256 + tid;
        int row = f >> 2, s = f & 3;
        int sg = s ^ ((row >> 1) & 3);
        pB[j] = Bh_g + (size_t)(n0 + row) * Kd + sg * 8;
        offB[j] = f * 8;
    }

    int g = lane >> 4, rr = lane & 15;

#define STAGE(buf, k0) do {                                            \
        gload16(pA[0] + (k0), &As[buf][offA[0]]);                      \
        gload16(pA[1] + (k0), &As[buf][offA[1]]);                      \
        gload16(pA[2] + (k0), &As[buf][offA[2]]);                      \
        gload16(pA[3] + (k0), &As[buf][offA[3]]);                      \
        gload16(pB[0] + (k0), &Bh[buf][offB[0]]);                      \
        gload16(pB[1] + (k0), &Bh[buf][offB[1]]);                      \
    } while (0)

    STAGE(0, 0);
    __syncthreads();

    int nIter = Kd >> 5;    // 64
    int cur = 0;
    for (int it = 0; it < nIter; ++it) {
        if (it + 1 < nIter) STAGE(cur ^ 1, (it + 1) * 32);

        bf16x8 av[4], bhv[4];
#pragma unroll
        for (int i = 0; i < 4; ++i) {
            int ra = wr * 64 + i * 16 + rr;
            // two swizzled 16B f32 slots -> 8 floats -> bf16x8
            f32x4 alo = *(const f32x4*)&As[cur][ra * 32 + ((2 * g) ^ (ra & 7)) * 4];
            f32x4 ahi = *(const f32x4*)&As[cur][ra * 32 + ((2 * g + 1) ^ (ra & 7)) * 4];
            u16x8 ua;
            ua[0] = f2b(alo[0]); ua[1] = f2b(alo[1]); ua[2] = f2b(alo[2]); ua[3] = f2b(alo[3]);
            ua[4] = f2b(ahi[0]); ua[5] = f2b(ahi[1]); ua[6] = f2b(ahi[2]); ua[7] = f2b(ahi[3]);
            av[i] = *(bf16x8*)&ua;
            int rb = wc * 64 + i * 16 + rr;
            bhv[i] = *(const bf16x8*)&Bh[cur][rb * 32 + ((g ^ ((rb >> 1) & 3)) * 8)];
        }
#pragma unroll
        for (int i = 0; i < 4; ++i)
#pragma unroll
            for (int j = 0; j < 4; ++j)
                acc[i][j] = __builtin_amdgcn_mfma_f32_16x16x32_bf16(av[i], bhv[j], acc[i][j], 0, 0, 0);

        __syncthreads();
        cur ^= 1;
    }
#undef STAGE

    int cg = lane >> 4, cr = lane & 15;
#pragma unroll
    for (int i = 0; i < 4; ++i)
#pragma unroll
        for (int j = 0; j < 4; ++j) {
            int colb = n0 + wc * 64 + j * 16 + cr;
            if (colb < Nvalid) {
#pragma unroll
                for (int r = 0; r < 4; ++r) {
                    int rowb = m0 + wr * 64 + i * 16 + cg * 4 + r;
                    Cout[(size_t)rowb * Cstride + colb] = f2b(acc[i][j][r]);
                }
            }
        }
}

// ---------------- 256x256 8-wave GEMM (final), BK=32, 4-buffer distance-2 pipeline ----------------
__global__ __launch_bounds__(512, 2) void gemm256(const unsigned short* __restrict__ A,
                                                  const unsigned short* __restrict__ Bm,
                                                  float* __restrict__ C,
                                                  int Kd, int Cstride) {
    __shared__ __attribute__((aligned(16))) unsigned short As[4][8192];
    __shared__ __attribute__((aligned(16))) unsigned short Bs[4][8192];
    int tid = threadIdx.x;
    int lane = tid & 63, wave = tid >> 6;
    int wm = wave >> 2, wn = wave & 3;

    int nwg = gridDim.x * gridDim.y;            // 256
    int bid = blockIdx.y * gridDim.x + blockIdx.x;
    int cpx = nwg >> 3;
    int swz = (bid & 7) * cpx + (bid >> 3);
    int bx = swz % gridDim.x, by = swz / gridDim.x;
    int m0 = by * 256, n0 = bx * 256;

    f32x4 acc[8][4];
#pragma unroll
    for (int i = 0; i < 8; ++i)
#pragma unroll
        for (int j = 0; j < 4; ++j) acc[i][j] = (f32x4){0.f, 0.f, 0.f, 0.f};

    const unsigned short* pA[2];
    const unsigned short* pB[2];
    int ldsoff[2];
#pragma unroll
    for (int j = 0; j < 2; ++j) {
        int f = j * 512 + tid;
        int row = f >> 2, s = f & 3;
        int sg = s ^ ((row >> 1) & 3);
        pA[j] = A + (size_t)(m0 + row) * Kd + sg * 8;
        pB[j] = Bm + (size_t)(n0 + row) * Kd + sg * 8;
        ldsoff[j] = (j * 512 + wave * 64) * 8;
    }

    int rr = lane & 15, kg = lane >> 4;

#define STAGE(buf, koff) do {                                          \
        gload16(pA[0] + (koff), &As[buf][ldsoff[0]]);                  \
        gload16(pA[1] + (koff), &As[buf][ldsoff[1]]);                  \
        gload16(pB[0] + (koff), &Bs[buf][ldsoff[0]]);                  \
        gload16(pB[1] + (koff), &Bs[buf][ldsoff[1]]);                  \
    } while (0)

    int nT = Kd >> 5;       // 24
    STAGE(0, 0);
    STAGE(1, 32);

#define LDA(fr) ({ int ra_ = wm * 128 + (fr) * 16 + rr;                          \
        *(const bf16x8*)&As[cur][ra_ * 32 + ((kg ^ ((ra_ >> 1) & 3)) * 8)]; })
#define LDB(fc) ({ int rb_ = wn * 64 + (fc) * 16 + rr;                           \
        *(const bf16x8*)&Bs[cur][rb_ * 32 + ((kg ^ ((rb_ >> 1) & 3)) * 8)]; })

    for (int it = 0; it < nT; ++it) {
        int cur = it & 3;
        if (it + 2 < nT) STAGE((it + 2) & 3, (it + 2) * 32);
        wait_stage(it, nT);
        __builtin_amdgcn_s_barrier();

        bf16x8 bv[4];
#pragma unroll
        for (int j = 0; j < 4; ++j) bv[j] = LDB(j);
#pragma unroll
        for (int i = 0; i < 8; ++i) {
            bf16x8 a0 = LDA(i);
#pragma unroll
            for (int j = 0; j < 4; ++j)
                acc[i][j] = __builtin_amdgcn_mfma_f32_16x16x32_bf16(a0, bv[j], acc[i][j], 0, 0, 0);
        }
    }
#undef LDA
#undef LDB
#undef STAGE

    int cg = lane >> 4;
#pragma unroll
    for (int i = 0; i < 8; ++i)
#pragma unroll
        for (int j = 0; j < 4; ++j) {
            int colb = n0 + wn * 64 + j * 16 + rr;
#pragma unroll
            for (int r = 0; r < 4; ++r) {
                int rowb = m0 + wm * 128 + i * 16 + cg * 4 + r;
                C[(size_t)rowb * Cstride + colb] = acc[i][j][r];
            }
        }
}

// ---------------- fused A: conv+trig chunk partial sums ----------------
__global__ __launch_bounds__(256) void fused_partial(const unsigned short* __restrict__ zq,
                                                     const float* __restrict__ conv_k,
                                                     const float* __restrict__ theta,
                                                     const float* __restrict__ decay,
                                                     const float* __restrict__ anchor,
                                                     const float* __restrict__ sscale,
                                                     float* __restrict__ partials) {
    int chunk = blockIdx.x, b = blockIdx.y, t = threadIdx.x;
    int l0 = chunk * CH;
    __shared__ unsigned short zin[CH + 3][CTOT];

    for (int idx = t; idx < (CH + 3) * 36; idx += 256) {
        int r = idx / 36, c8 = (idx % 36) * 8;
        int l = l0 - 3 + r;
        u16x8 v = (u16x8)(0);
        if (l >= 0) v = *(const u16x8*)&zq[(size_t)(b * LL + l) * ZSTR + c8];
        *(u16x8*)&zin[r][c8] = v;
    }
    __syncthreads();

    int k = t >> 3;
    float cz0 = conv_k[t], cz1 = conv_k[CTOT + t], cz2 = conv_k[2 * CTOT + t], cz3 = conv_k[3 * CTOT + t];
    int sc = MEM + k;
    float cs0 = conv_k[sc], cs1 = conv_k[CTOT + sc], cs2 = conv_k[2 * CTOT + sc], cs3 = conv_k[3 * CTOT + sc];
    float xx = (k < KK - 4) ? decay[k] : anchor[k - (KK - 4)];
    float sp = (xx > 20.f) ? xx : log1pf(__expf(xx));
    float ss = sscale[k];
    float th[8];
#pragma unroll
    for (int m = 0; m < 8; ++m) th[m] = theta[t * 8 + m];
    float rs[8], is[8];
#pragma unroll
    for (int m = 0; m < 8; ++m) { rs[m] = 0.f; is[m] = 0.f; }
    float dsum = 0.f;

#pragma unroll 1
    for (int i = 0; i < CH; ++i) {
        float kv = b2f(zin[i][t]) * cz0 + b2f(zin[i + 1][t]) * cz1 +
                   b2f(zin[i + 2][t]) * cz2 + b2f(zin[i + 3][t]) * cz3;
        float s = b2f(zin[i][sc]) * cs0 + b2f(zin[i + 1][sc]) * cs1 +
                  b2f(zin[i + 2][sc]) * cs2 + b2f(zin[i + 3][sc]) * cs3;
        int l = l0 + i;
        float lw = (k < KK - 4) ? -sp * (float)(LL - 1 - l) : -sp * (float)l;
        float lp = fminf(fmaxf(ss * s, -20.f), 20.f);
        float p = __expf(lp + lw);
        dsum += p;
#pragma unroll
        for (int m = 0; m < 8; ++m) {
            float sn, cn;
            __sincosf(kv * th[m], &sn, &cn);
            rs[m] += p * cn;
            is[m] += p * sn;
        }
    }
    size_t base = ((size_t)b * NCH + chunk) * CMERG;
    *(f32x4*)&partials[base + KK + t * 8]            = (f32x4){rs[0], rs[1], rs[2], rs[3]};
    *(f32x4*)&partials[base + KK + t * 8 + 4]        = (f32x4){rs[4], rs[5], rs[6], rs[7]};
    *(f32x4*)&partials[base + KK + FLAT + t * 8]     = (f32x4){is[0], is[1], is[2], is[3]};
    *(f32x4*)&partials[base + KK + FLAT + t * 8 + 4] = (f32x4){is[4], is[5], is[6], is[7]};
    if ((t & 7) == 0) partials[base + k] = dsum;
}

// ---------------- fused B: exclusive scan of chunk partials (in place) ----------------
__global__ __launch_bounds__(256) void scan_partials(float* __restrict__ partials) {
    int t = threadIdx.x;
    int cl = t & 15, j = t >> 4;
    int c = blockIdx.x * 16 + cl;
    int b = blockIdx.y;
    float v[16];
    float s = 0.f;
#pragma unroll
    for (int i = 0; i < 16; ++i) {
        v[i] = partials[((size_t)b * NCH + j * 16 + i) * CMERG + c];
        s += v[i];
    }
    __shared__ float sums[16][17];
    sums[j][cl] = s;
    __syncthreads();
    if (j == 0) {
        float run = 0.f;
#pragma unroll
        for (int jj = 0; jj < 16; ++jj) {
            float x = sums[jj][cl];
            sums[jj][cl] = run;
            run += x;
        }
    }
    __syncthreads();
    float run = sums[j][cl];
#pragma unroll
    for (int i = 0; i < 16; ++i) {
        float x = v[i];
        partials[((size_t)b * NCH + j * 16 + i) * CMERG + c] = run;
        run += x;
    }
}

// ---------------- fused C: recompute + in-register scan + stage_d ----------------
__global__ __launch_bounds__(256) void fused_stage(const unsigned short* __restrict__ zq,
                                                   const float* __restrict__ conv_k,
                                                   const float* __restrict__ theta,
                                                   const float* __restrict__ decay,
                                                   const float* __restrict__ anchor,
                                                   const float* __restrict__ sscale,
                                                   const float* __restrict__ partials,
                                                   const float* __restrict__ W_re,
                                                   const float* __restrict__ W_im,
                                                   const float* __restrict__ nscale,
                                                   unsigned short* __restrict__ y_act) {
    int chunk = blockIdx.x, b = blockIdx.y, t = threadIdx.x;
    int l0 = chunk * CH;
    __shared__ unsigned short zin[CH + 3][CTOT];
    __shared__ unsigned short qall[CH][NQ];

    for (int idx = t; idx < (CH + 3) * 36; idx += 256) {
        int r = idx / 36, c8 = (idx % 36) * 8;
        int l = l0 - 3 + r;
        u16x8 v = (u16x8)(0);
        if (l >= 0) v = *(const u16x8*)&zq[(size_t)(b * LL + l) * ZSTR + c8];
        *(u16x8*)&zin[r][c8] = v;
    }
    for (int idx = t; idx < CH * (NQ / 8); idx += 256) {
        int i = idx >> 6, c8 = (idx & 63) * 8;
        *(u16x8*)&qall[i][c8] = *(const u16x8*)&zq[(size_t)(b * LL + l0 + i) * ZSTR + CTOT + c8];
    }
    __syncthreads();

    int k = t >> 3, h = t & 7, w = t >> 6;
    float cz0 = conv_k[t], cz1 = conv_k[CTOT + t], cz2 = conv_k[2 * CTOT + t], cz3 = conv_k[3 * CTOT + t];
    int sc = MEM + k;
    float cs0 = conv_k[sc], cs1 = conv_k[CTOT + sc], cs2 = conv_k[2 * CTOT + sc], cs3 = conv_k[3 * CTOT + sc];
    float xx = (k < KK - 4) ? decay[k] : anchor[k - (KK - 4)];
    float sp = (xx > 20.f) ? xx : log1pf(__expf(xx));
    float ss = sscale[k];
    float th[8];
#pragma unroll
    for (int m = 0; m < 8; ++m) th[m] = theta[t * 8 + m];
    float ns = nscale[t];
    int qb = w * 128 + h * 16;

    float wre[8][6], wim[8][6];
#pragma unroll
    for (int hh = 0; hh < 8; ++hh)
#pragma unroll
        for (int jj = 0; jj < 6; ++jj) {
            wre[hh][jj] = W_re[(k * 8 + hh) * 48 + h + 8 * jj];
            wim[hh][jj] = W_im[(k * 8 + hh) * 48 + h + 8 * jj];
        }

    size_t pbase = ((size_t)b * NCH + chunk) * CMERG;
    f32x4 r0 = *(const f32x4*)&partials[pbase + KK + t * 8];
    f32x4 r1 = *(const f32x4*)&partials[pbase + KK + t * 8 + 4];
    f32x4 i0 = *(const f32x4*)&partials[pbase + KK + FLAT + t * 8];
    f32x4 i1 = *(const f32x4*)&partials[pbase + KK + FLAT + t * 8 + 4];
    float rs[8] = {r0[0], r0[1], r0[2], r0[3], r1[0], r1[1], r1[2], r1[3]};
    float is[8] = {i0[0], i0[1], i0[2], i0[3], i1[0], i1[1], i1[2], i1[3]};
    float den = partials[pbase + k];

#pragma unroll 1
    for (int i = 0; i < CH; ++i) {
        float kv = b2f(zin[i][t]) * cz0 + b2f(zin[i + 1][t]) * cz1 +
                   b2f(zin[i + 2][t]) * cz2 + b2f(zin[i + 3][t]) * cz3;
        float s = b2f(zin[i][sc]) * cs0 + b2f(zin[i + 1][sc]) * cs1 +
                  b2f(zin[i + 2][sc]) * cs2 + b2f(zin[i + 3][sc]) * cs3;
        int l = l0 + i;
        float lw = (k < KK - 4) ? -sp * (float)(LL - 1 - l) : -sp * (float)l;
        float lp = fminf(fmaxf(ss * s, -20.f), 20.f);
        float p = __expf(lp + lw);
        den += p;
        float inv = __builtin_amdgcn_rcpf(fmaxf(den, 1e-4f));
#pragma unroll
        for (int m = 0; m < 8; ++m) {
            float sn, cn;
            __sincosf(kv * th[m], &sn, &cn);
            rs[m] += p * cn;
            is[m] += p * sn;
        }
        u16x8 qv0 = *(const u16x8*)&qall[i][qb];
        u16x8 qv1 = *(const u16x8*)&qall[i][qb + 8];
        float o_re = 0.f, o_im = 0.f;
#pragma unroll
        for (int m = 0; m < 8; ++m) {
            float sre = rs[m] * inv;
            float sim = is[m] * inv;
            float qre = b2f((unsigned short)((m < 4) ? qv0[2 * m] : qv1[2 * m - 8]));
            float qim = b2f((unsigned short)((m < 4) ? qv0[2 * m + 1] : qv1[2 * m - 7]));
            o_re += sre * qre + sim * qim;
            o_im += sim * qre - sre * qim;
        }
        o_re *= ns;
        o_im *= ns;

        float y0 = 0.f, y1 = 0.f, y2 = 0.f, y3 = 0.f, y4 = 0.f, y5 = 0.f;
#define EAPPLY(HH) { float br_ = bcast8<HH>(o_re); float bi_ = bcast8<HH>(o_im); \
        y0 += br_ * wre[HH][0] + bi_ * wim[HH][0]; \
        y1 += br_ * wre[HH][1] + bi_ * wim[HH][1]; \
        y2 += br_ * wre[HH][2] + bi_ * wim[HH][2]; \
        y3 += br_ * wre[HH][3] + bi_ * wim[HH][3]; \
        y4 += br_ * wre[HH][4] + bi_ * wim[HH][4]; \
        y5 += br_ * wre[HH][5] + bi_ * wim[HH][5]; }
        EAPPLY(0) EAPPLY(1) EAPPLY(2) EAPPLY(3)
        EAPPLY(4) EAPPLY(5) EAPPLY(6) EAPPLY(7)
#undef EAPPLY

        size_t ybase = (size_t)(b * LL + l) * YDIM + k * 24 + h;
        y_act[ybase]      = f2b(fast_sigmoid_mul(y0 * y3, y3));
        y_act[ybase + 8]  = f2b(fast_sigmoid_mul(y1 * y4, y4));
        y_act[ybase + 16] = f2b(fast_sigmoid_mul(y2 * y5, y5));
    }
}

extern "C" void kernel_launch(void* const* d_in, const int* in_sizes, int n_in,
                              void* d_out, int out_size, void* d_ws, size_t ws_size,
                              hipStream_t stream) {
    const float* x      = (const float*)d_in[0];
    const float* W_mem  = (const float*)d_in[1];
    const float* conv_k = (const float*)d_in[2];
    const float* W_q    = (const float*)d_in[3];
    const float* theta  = (const float*)d_in[4];
    const float* decay  = (const float*)d_in[5];
    const float* anchor = (const float*)d_in[6];
    const float* sscale = (const float*)d_in[7];
    const float* W_re   = (const float*)d_in[8];
    const float* W_im   = (const float*)d_in[9];
    const float* nscale = (const float*)d_in[10];
    const float* W_out  = (const float*)d_in[11];
    float* out = (float*)d_out;
    float* ws = (float*)d_ws;

    // ---- d_out stash (dead before final GEMM writes d_out) ----
    unsigned short* Wb = (unsigned short*)out;                 // 896*2048 bf16 = 917,504 float slots
    unsigned short* zq = (unsigned short*)(out + 917504);      // 8192*800 bf16 = 3,276,800 slots, ends 4,194,304
    // ---- ws (offsets in float slots) ----
    float* partials      = ws;                                 // 2*256*4128 = 2,113,536 floats
    unsigned short* yb   = (unsigned short*)(ws + 2113536);    // 8192*768 bf16 = 3,145,728 float slots
    unsigned short* Wo   = (unsigned short*)(ws + 5259264);    // 2048*768 bf16 = 786,432 float slots
                                                               // ends 6,045,696 floats (24.2 MB)

    prep_wb<<<NPAD, 256, 0, stream>>>(W_mem, W_q, Wb);
    prep_wo<<<DD, 256, 0, stream>>>(W_out, Wo);

    // 1) zq = x @ [W_mem | W_q]   (8192 x 800 x 2048), f32 A staged+converted in-kernel
    gemm_zq<<<dim3(NPAD / 128, BL / 128), 256, 0, stream>>>(
        x, Wb, zq, DD, ZSTR, ZSTR);
    // 2) chunk partial sums (conv+trig recompute, registers only)
    fused_partial<<<dim3(NCH, BB), 256, 0, stream>>>(zq, conv_k, theta, decay, anchor, sscale, partials);
    // 3) exclusive scan of chunk partials
    scan_partials<<<dim3(CMERG / 16, BB), 256, 0, stream>>>(partials);
    // 4) recompute + in-register inclusive scan + fused stage_d -> y (bf16)
    fused_stage<<<dim3(NCH, BB), 256, 0, stream>>>(zq, conv_k, theta, decay, anchor, sscale,
                                                   partials, W_re, W_im, nscale, yb);
    // 5) out = y @ Wo^T  (8192 x 2048 x 768), single-bf16 B
    gemm256<<<dim3(DD / 256, BL / 256), 512, 0, stream>>>(yb, Wo, out, YDIM, DD);
}